// Round 6
// baseline (81.428 us; speedup 1.0000x reference)
//
#include <hip/hip_runtime.h>
#include <hip/hip_cooperative_groups.h>
#include <math.h>

namespace cg = cooperative_groups;

#define N_ROWS 8192   // SIZE
#define N_COLS 1024   // M
#define NBLK   256    // 1 block per CU -> cooperative co-residency trivially OK
#define NTHR   1024
#define RPB    32     // rows per block; ex tile = 32*1024*4 = 128 KB LDS

// out[i,j] = log(S[j] + (exp(diag[i]) - 1) * exp(x[i,j])),  S[j] = sum_i exp(x[i,j])
// (x ~ N(0,1): sum_i exp(x) ~ 1.4e4, no overflow -> no max-stabilization needed;
//  validated absmax 0.0625 vs threshold 0.19 in rounds 1-4.)
__global__ __launch_bounds__(NTHR, 4) void fused_logmatexp(
    const float* __restrict__ x, const float* __restrict__ diag,
    float* __restrict__ ps,    // [NBLK][N_COLS] block column partials
    float* __restrict__ S,     // [N_COLS]
    float* __restrict__ out)
{
    cg::grid_group grid = cg::this_grid();
    __shared__ float ex[RPB][N_COLS];    // 128 KB: exp(x) tile, held across syncs
    __shared__ float red[4][N_COLS];     // 16 KB: phase-1 cross-rowgroup reduce
    __shared__ float redS[16];

    const int t    = threadIdx.x;
    const int b    = blockIdx.x;
    const int col0 = (t & 255) * 4;      // 4 cols per thread (float4)
    const int rg   = t >> 8;             // row-group 0..3 (8 rows each)
    const int r0   = rg * 8;
    const int row0 = b * RPB + r0;

    // ---- Phase 1: stream x -> exp -> LDS; block column partials -> ps ----
    float4 s4 = make_float4(0.f, 0.f, 0.f, 0.f);
#pragma unroll
    for (int k = 0; k < 8; ++k) {
        const float4 v = *reinterpret_cast<const float4*>(
            x + (size_t)(row0 + k) * N_COLS + col0);
        float4 e;
        e.x = __expf(v.x); e.y = __expf(v.y);
        e.z = __expf(v.z); e.w = __expf(v.w);
        *reinterpret_cast<float4*>(&ex[r0 + k][col0]) = e;
        s4.x += e.x; s4.y += e.y; s4.z += e.z; s4.w += e.w;
    }
    *reinterpret_cast<float4*>(&red[rg][col0]) = s4;
    __syncthreads();
    if (t < 256) {   // rg==0: col0 == t*4
        float4 a = *reinterpret_cast<const float4*>(&red[0][col0]);
        const float4 b1 = *reinterpret_cast<const float4*>(&red[1][col0]);
        const float4 b2 = *reinterpret_cast<const float4*>(&red[2][col0]);
        const float4 b3 = *reinterpret_cast<const float4*>(&red[3][col0]);
        a.x += b1.x + b2.x + b3.x;  a.y += b1.y + b2.y + b3.y;
        a.z += b1.z + b2.z + b3.z;  a.w += b1.w + b2.w + b3.w;
        *reinterpret_cast<float4*>(ps + (size_t)b * N_COLS + col0) = a;
    }

    grid.sync();

    // ---- Phase 2: block b reduces columns 4b..4b+3 of ps -> S ----
    {
        const int g    = t >> 8;         // which of the 4 columns
        const int sub  = t & 255;        // chunk index
        const int col  = b * 4 + g;
        const int lane = t & 63;
        const int wid  = t >> 6;
        float s = ps[(size_t)sub * N_COLS + col];
#pragma unroll
        for (int off = 32; off; off >>= 1) s += __shfl_down(s, off);
        if (lane == 0) redS[wid] = s;
        __syncthreads();
        if (sub == 0)
            S[col] = redS[4 * g + 0] + redS[4 * g + 1] +
                     redS[4 * g + 2] + redS[4 * g + 3];
    }

    grid.sync();

    // ---- Phase 3: finalize from LDS, float4 stores ----
    const float4 Sj = *reinterpret_cast<const float4*>(S + col0);
#pragma unroll
    for (int k = 0; k < 8; ++k) {
        const int row = row0 + k;
        const float E = __expf(diag[row]) - 1.f;   // wave-uniform
        const float4 e = *reinterpret_cast<const float4*>(&ex[r0 + k][col0]);
        float4 o;
        o.x = __logf(fmaf(E, e.x, Sj.x));
        o.y = __logf(fmaf(E, e.y, Sj.y));
        o.z = __logf(fmaf(E, e.z, Sj.z));
        o.w = __logf(fmaf(E, e.w, Sj.w));
        *reinterpret_cast<float4*>(out + (size_t)row * N_COLS + col0) = o;
    }
}

// ---------------- Fallback path (round-4, proven 26.6 us) ----------------
__global__ __launch_bounds__(1024) void colsum_part(
    const float* __restrict__ x, float* __restrict__ ps) {
    const int b    = blockIdx.x;
    const int t    = threadIdx.x;
    const int col0 = (t & 255) * 4;
    const int rg   = t >> 8;
    const int row0 = b * 32 + rg * 8;

    float4 s4 = make_float4(0.f, 0.f, 0.f, 0.f);
#pragma unroll
    for (int k = 0; k < 8; ++k) {
        const float4 v = *reinterpret_cast<const float4*>(
            x + (size_t)(row0 + k) * N_COLS + col0);
        s4.x += __expf(v.x); s4.y += __expf(v.y);
        s4.z += __expf(v.z); s4.w += __expf(v.w);
    }
    __shared__ float red[4][N_COLS];
    *reinterpret_cast<float4*>(&red[rg][col0]) = s4;
    __syncthreads();
    ps[(size_t)b * N_COLS + t] = red[0][t] + red[1][t] + red[2][t] + red[3][t];
}

__global__ __launch_bounds__(1024) void merge_finalize(
    const float* __restrict__ x, const float* __restrict__ diag,
    const float* __restrict__ ps, float* __restrict__ out) {
    const int cs = blockIdx.x & 3;
    const int rb = blockIdx.x >> 2;
    const int c0 = cs * 256;
    const int t  = threadIdx.x;

    __shared__ float red[4][256];
    __shared__ float S[256];
    {
        const int cg = t >> 8;
        const int c  = t & 255;
        float s = 0.f;
#pragma unroll 8
        for (int k = 0; k < 64; ++k)
            s += ps[(size_t)(cg * 64 + k) * N_COLS + c0 + c];
        red[cg][c] = s;
    }
    __syncthreads();
    if (t < 256) S[t] = red[0][t] + red[1][t] + red[2][t] + red[3][t];
    __syncthreads();

    const int lane = t & 63;
    const int w    = t >> 6;
    const int r0   = rb * 128 + w * 8;
    const float4 Sj = *reinterpret_cast<const float4*>(&S[4 * lane]);

#pragma unroll
    for (int k = 0; k < 8; ++k) {
        const int row = r0 + k;
        const float E = __expf(diag[row]) - 1.f;
        const size_t off = (size_t)row * N_COLS + c0 + 4 * lane;
        const float4 v = *reinterpret_cast<const float4*>(x + off);
        float4 o;
        o.x = __logf(fmaf(E, __expf(v.x), Sj.x));
        o.y = __logf(fmaf(E, __expf(v.y), Sj.y));
        o.z = __logf(fmaf(E, __expf(v.z), Sj.z));
        o.w = __logf(fmaf(E, __expf(v.w), Sj.w));
        *reinterpret_cast<float4*>(out + off) = o;
    }
}

extern "C" void kernel_launch(void* const* d_in, const int* in_sizes, int n_in,
                              void* d_out, int out_size, void* d_ws, size_t ws_size,
                              hipStream_t stream) {
    const float* x    = (const float*)d_in[0];   // [8192, 1024] f32
    const float* diag = (const float*)d_in[1];   // [8192] f32
    float* out = (float*)d_out;                  // [8192, 1024] f32
    float* ws  = (float*)d_ws;

    float* ps = ws;                      // NBLK * N_COLS = 1 MB
    float* S  = ps + NBLK * N_COLS;      // N_COLS

    void* args[] = { (void*)&x, (void*)&diag, (void*)&ps, (void*)&S, (void*)&out };
    hipError_t err = hipLaunchCooperativeKernel((const void*)fused_logmatexp,
                                                dim3(NBLK), dim3(NTHR), args, 0, stream);
    if (err != hipSuccess) {
        // Deterministic fallback: proven 2-kernel path.
        colsum_part<<<256, 1024, 0, stream>>>(x, ps);
        merge_finalize<<<256, 1024, 0, stream>>>(x, diag, ps, out);
    }
}

// Round 7
// 30.051 us; speedup vs baseline: 2.7097x; 2.7097x over previous
//
#include <hip/hip_runtime.h>
#include <math.h>

#define N_ROWS 8192   // SIZE
#define N_COLS 1024   // M

// K1: S[j] += sum over rows [32b, 32b+32) of exp(x[i][j])   (atomic accumulate)
// Grid: 256 blocks x 1024 threads. Thread (rg = t>>8, cgi = t&255) owns
// 8 rows x 4 cols (float4). LDS reduce across the 4 row-groups, then one
// atomicAdd per column (256 adds per address across the whole grid).
__global__ __launch_bounds__(1024) void colsum_atomic(
    const float* __restrict__ x, float* __restrict__ S) {
    const int b    = blockIdx.x;
    const int t    = threadIdx.x;
    const int col0 = (t & 255) * 4;
    const int rg   = t >> 8;            // 0..3
    const int row0 = b * 32 + rg * 8;

    float4 s4 = make_float4(0.f, 0.f, 0.f, 0.f);
#pragma unroll
    for (int k = 0; k < 8; ++k) {
        const float4 v = *reinterpret_cast<const float4*>(
            x + (size_t)(row0 + k) * N_COLS + col0);
        s4.x += __expf(v.x); s4.y += __expf(v.y);
        s4.z += __expf(v.z); s4.w += __expf(v.w);
    }

    __shared__ float red[4][N_COLS];    // 16 KB
    *reinterpret_cast<float4*>(&red[rg][col0]) = s4;   // contiguous per wave
    __syncthreads();
    // thread t owns column t: fold 4 row-groups, one global atomic
    const float s = red[0][t] + red[1][t] + red[2][t] + red[3][t];
    atomicAdd(&S[t], s);
}

// K2: pure streaming finalize.
//   out[i,j] = log(S[j] + (exp(diag[i]) - 1) * exp(x[i,j]))
// Grid: 256 blocks x 1024 threads; same tiling as K1 (32 rows x 1024 cols per
// block, 8 rows x 4 cols per thread). No LDS, no barriers.
__global__ __launch_bounds__(1024) void finalize_stream(
    const float* __restrict__ x, const float* __restrict__ diag,
    const float* __restrict__ S, float* __restrict__ out) {
    const int b    = blockIdx.x;
    const int t    = threadIdx.x;
    const int col0 = (t & 255) * 4;
    const int rg   = t >> 8;
    const int row0 = b * 32 + rg * 8;

    const float4 Sj = *reinterpret_cast<const float4*>(S + col0);  // L2-hot 4 KB

#pragma unroll
    for (int k = 0; k < 8; ++k) {
        const int row = row0 + k;
        const float E = __expf(diag[row]) - 1.f;   // wave-uniform scalar path
        const size_t off = (size_t)row * N_COLS + col0;
        const float4 v = *reinterpret_cast<const float4*>(x + off);
        float4 o;
        o.x = __logf(fmaf(E, __expf(v.x), Sj.x));
        o.y = __logf(fmaf(E, __expf(v.y), Sj.y));
        o.z = __logf(fmaf(E, __expf(v.z), Sj.z));
        o.w = __logf(fmaf(E, __expf(v.w), Sj.w));
        *reinterpret_cast<float4*>(out + off) = o;
    }
}

extern "C" void kernel_launch(void* const* d_in, const int* in_sizes, int n_in,
                              void* d_out, int out_size, void* d_ws, size_t ws_size,
                              hipStream_t stream) {
    const float* x    = (const float*)d_in[0];   // [8192, 1024] f32
    const float* diag = (const float*)d_in[1];   // [8192] f32
    float* out = (float*)d_out;                  // [8192, 1024] f32
    float* S   = (float*)d_ws;                   // [1024] f32 accumulator

    hipMemsetAsync(S, 0, N_COLS * sizeof(float), stream);  // async: capture-safe
    colsum_atomic<<<256, 1024, 0, stream>>>(x, S);
    finalize_stream<<<256, 1024, 0, stream>>>(x, diag, S, out);
}

// Round 9
// 29.591 us; speedup vs baseline: 2.7518x; 1.0155x over previous
//
#include <hip/hip_runtime.h>
#include <math.h>

#define N_ROWS 8192   // SIZE
#define N_COLS 1024   // M

typedef float f32x4 __attribute__((ext_vector_type(4)));  // native vec for nontemporal builtin

// K1 (unchanged from round 4, proven): ps[b][j] = sum_{i in [32b,32b+32)} exp(x[i][j]).
// Grid: 256 blocks x 1024 threads.
__global__ __launch_bounds__(1024) void colsum_part(
    const float* __restrict__ x, float* __restrict__ ps) {
    const int b    = blockIdx.x;
    const int t    = threadIdx.x;
    const int col0 = (t & 255) * 4;
    const int rg   = t >> 8;            // 0..3
    const int row0 = b * 32 + rg * 8;

    float4 s4 = make_float4(0.f, 0.f, 0.f, 0.f);
#pragma unroll
    for (int k = 0; k < 8; ++k) {
        const float4 v = *reinterpret_cast<const float4*>(
            x + (size_t)(row0 + k) * N_COLS + col0);
        s4.x += __expf(v.x); s4.y += __expf(v.y);
        s4.z += __expf(v.z); s4.w += __expf(v.w);
    }
    __shared__ float red[4][N_COLS];    // 16 KB
    *reinterpret_cast<float4*>(&red[rg][col0]) = s4;
    __syncthreads();
    ps[(size_t)b * N_COLS + t] = red[0][t] + red[1][t] + red[2][t] + red[3][t];
}

// K2: T14 issue-early variant.
//   pre-barrier: issue 8 x-float4 loads + diag loads, compute exps into regs
//   phase A:     S[c] = sum over 256 chunks of ps (coalesced) + LDS reduce
//   post:        out = log(fma(E, e, Sj)), nontemporal float4 stores
__global__ __launch_bounds__(1024) void merge_finalize(
    const float* __restrict__ x, const float* __restrict__ diag,
    const float* __restrict__ ps, float* __restrict__ out) {
    const int cs = blockIdx.x & 3;
    const int rb = blockIdx.x >> 2;
    const int c0 = cs * 256;
    const int t  = threadIdx.x;
    const int lane = t & 63;
    const int w    = t >> 6;            // 16 waves, 8 rows each
    const int r0   = rb * 128 + w * 8;
    const int col  = c0 + 4 * lane;

    // ---- issue-early: all 8 tile loads in flight before phase A ----
    float4 v[8];
#pragma unroll
    for (int k = 0; k < 8; ++k)
        v[k] = *reinterpret_cast<const float4*>(
            x + (size_t)(r0 + k) * N_COLS + col);
    float E[8];
#pragma unroll
    for (int k = 0; k < 8; ++k)
        E[k] = __expf(diag[r0 + k]) - 1.f;   // wave-uniform scalar path
#pragma unroll
    for (int k = 0; k < 8; ++k) {            // in-place e = exp(x)
        v[k].x = __expf(v[k].x); v[k].y = __expf(v[k].y);
        v[k].z = __expf(v[k].z); v[k].w = __expf(v[k].w);
    }

    // ---- phase A: column sums of ps for this stripe ----
    __shared__ float red[4][256];       // 4 KB
    __shared__ float S[256];            // 1 KB
    {
        const int cg = t >> 8;          // chunk-group 0..3 (64 chunks each)
        const int c  = t & 255;
        float s = 0.f;
#pragma unroll 8
        for (int k = 0; k < 64; ++k)
            s += ps[(size_t)(cg * 64 + k) * N_COLS + c0 + c];
        red[cg][c] = s;
    }
    __syncthreads();
    if (t < 256) S[t] = red[0][t] + red[1][t] + red[2][t] + red[3][t];
    __syncthreads();

    // ---- finalize from registers ----
    const float4 Sj = *reinterpret_cast<const float4*>(&S[4 * lane]);
#pragma unroll
    for (int k = 0; k < 8; ++k) {
        f32x4 o;
        o.x = __logf(fmaf(E[k], v[k].x, Sj.x));
        o.y = __logf(fmaf(E[k], v[k].y, Sj.y));
        o.z = __logf(fmaf(E[k], v[k].z, Sj.z));
        o.w = __logf(fmaf(E[k], v[k].w, Sj.w));
        __builtin_nontemporal_store(
            o, reinterpret_cast<f32x4*>(out + (size_t)(r0 + k) * N_COLS + col));
    }
}

extern "C" void kernel_launch(void* const* d_in, const int* in_sizes, int n_in,
                              void* d_out, int out_size, void* d_ws, size_t ws_size,
                              hipStream_t stream) {
    const float* x    = (const float*)d_in[0];   // [8192, 1024] f32
    const float* diag = (const float*)d_in[1];   // [8192] f32
    float* out = (float*)d_out;                  // [8192, 1024] f32
    float* ps  = (float*)d_ws;                   // [256][1024] f32 = 1 MB

    colsum_part<<<256, 1024, 0, stream>>>(x, ps);
    merge_finalize<<<256, 1024, 0, stream>>>(x, diag, ps, out);
}